// Round 1
// baseline (28443.170 us; speedup 1.0000x reference)
//
#include <hip/hip_runtime.h>

// ---------------------------------------------------------------------------
// CNF (continuous normalizing flow) forward: 2 blocks x Tsit5(10 steps x 6
// stages), each stage: f32 forward MLP (512x[129-512-512-512-128]) + exact
// Jacobian trace via bf16 MFMA propagation of J in [hid=512, in=128] per
// sample, batched over 512 samples.
// ---------------------------------------------------------------------------

using short8  = __attribute__((ext_vector_type(8))) short;
using u16x8   = __attribute__((ext_vector_type(8))) unsigned short;
using f32x4v  = __attribute__((ext_vector_type(4))) float;

__device__ inline unsigned short f2bf(float f) {
  union { float f; unsigned u; } v; v.f = f;
  unsigned r = v.u + 0x7fffu + ((v.u >> 16) & 1u);
  return (unsigned short)(r >> 16);
}

struct Coef5 { float v[5]; };
struct Coef6 { float v[6]; };

// ---------------------------------------------------------------------------
__global__ __launch_bounds__(256) void init_state(const float* __restrict__ y_in,
                                                  float* __restrict__ y,
                                                  float* __restrict__ lp) {
  int i = blockIdx.x * 256 + threadIdx.x;
  if (i < 512 * 128) y[i] = y_in[i];
  if (i < 512) lp[i] = 0.f;
}

// Cast/transpose weights for the Jacobian path (per block).
// w0y[j][a] = bf16(W0[1+j][a])           (128x512)
// w1t[b][a] = bf16(W1[a][b])             (512x512)
// w2t[c][b] = bf16(W2[b][c])             (512x512)
__global__ __launch_bounds__(256) void cast_weights(const float* __restrict__ W0,
                                                    const float* __restrict__ W1,
                                                    const float* __restrict__ W2,
                                                    unsigned short* __restrict__ w0y,
                                                    unsigned short* __restrict__ w1t,
                                                    unsigned short* __restrict__ w2t) {
  int i = blockIdx.x * 256 + threadIdx.x;
  if (i < 65536) {
    int j = i >> 9, a = i & 511;
    w0y[i] = f2bf(W0[(1 + j) * 512 + a]);
  } else if (i < 65536 + 262144) {
    int k = i - 65536; int b = k >> 9, a = k & 511;
    w1t[k] = f2bf(W1[a * 512 + b]);
  } else if (i < 65536 + 2 * 262144) {
    int k = i - 65536 - 262144; int c = k >> 9, b = k & 511;
    w2t[k] = f2bf(W2[b * 512 + c]);
  }
}

// yi = y + sum_{j<nc} c[j]*ky[j]; also zero this stage's klp partials (4x512).
__global__ __launch_bounds__(256) void prep_stage(const float* __restrict__ y,
                                                  const float* __restrict__ ky,
                                                  float* __restrict__ yi,
                                                  float* __restrict__ klp_part,
                                                  Coef5 c, int nc) {
  int i = blockIdx.x * 256 + threadIdx.x;
  if (i < 65536) {
    float a = y[i];
    for (int j = 0; j < nc; ++j) a += c.v[j] * ky[j * 65536 + i];
    yi[i] = a;
  }
  if (i < 2048) klp_part[i] = 0.f;
}

// f32 SIMT GEMM: C[M,N] = act(A[M,K] @ W[K,N] + bias (+ t*wrow0 if L0)).
// 64x64 tile, BK=16, 256 threads, 4x4 per thread.
template <bool RELU, bool L0>
__global__ __launch_bounds__(256) void fwd_gemm(const float* __restrict__ A,
                                                const float* __restrict__ W,
                                                const float* __restrict__ bias,
                                                const float* __restrict__ wrow0,
                                                float tval, float* __restrict__ C,
                                                int M, int N, int K) {
  __shared__ float As[64][20];
  __shared__ float Bs[16][64];
  const int tx = threadIdx.x & 15, ty = threadIdx.x >> 4;
  const int m0 = blockIdx.y * 64, n0 = blockIdx.x * 64;
  float acc[4][4] = {};
  const int ai = threadIdx.x * 4;
  const int am = ai >> 4, ak = ai & 15;         // A tile: 64 rows x 16 k
  const int bk = threadIdx.x >> 4, bn = (threadIdx.x & 15) * 4;  // B: 16 x 64
  for (int k0 = 0; k0 < K; k0 += 16) {
    float4 av = *(const float4*)&A[(m0 + am) * K + k0 + ak];
    float4 bv = *(const float4*)&W[(k0 + bk) * N + n0 + bn];
    __syncthreads();
    *(float4*)&As[am][ak] = av;
    *(float4*)&Bs[bk][bn] = bv;
    __syncthreads();
#pragma unroll
    for (int k = 0; k < 16; ++k) {
      float a[4], b[4];
#pragma unroll
      for (int r = 0; r < 4; ++r) a[r] = As[ty * 4 + r][k];
#pragma unroll
      for (int cc = 0; cc < 4; ++cc) b[cc] = Bs[k][tx * 4 + cc];
#pragma unroll
      for (int r = 0; r < 4; ++r)
#pragma unroll
        for (int cc = 0; cc < 4; ++cc) acc[r][cc] = fmaf(a[r], b[cc], acc[r][cc]);
    }
  }
#pragma unroll
  for (int r = 0; r < 4; ++r) {
    int m = m0 + ty * 4 + r;
    float ov[4];
#pragma unroll
    for (int cc = 0; cc < 4; ++cc) {
      int n = n0 + tx * 4 + cc;
      float be = bias[n];
      if (L0) be = fmaf(tval, wrow0[n], be);
      float v = acc[r][cc] + be;
      if (RELU) v = fmaxf(v, 0.f);
      ov[cc] = v;
    }
    *(float4*)&C[m * N + n0 + tx * 4] = *(float4*)ov;
  }
}

// ---------------------------------------------------------------------------
// Jacobian MFMA GEMMs. 16x16x32 bf16 MFMA, tile 128x128, 4 waves (2x2),
// BK=32, K=512, one sample per blockIdx.x, tile index blockIdx.y (4).
//
// MODE 0 (jacA): C[j][b] = D1[b] * sum_a (D0[a]*W0y[j][a]) * W1[a][b]
//   A = w0y rows j (masked by h0 sign along k=a), B tile = w1t rows b.
//   Output: J1T[s][j][b] bf16.
// MODE 1 (jacB): T[c][j] = sum_b W2[b][c] * J1[b][j];
//   klp_part[tile][s] = sum_{c,j in tile} (h2[c]>0) * W3[c][j] * T[c][j]
//   A = w2t rows c, B tile = J1T[s] rows j.
// ---------------------------------------------------------------------------
template <int MODE>
__global__ __launch_bounds__(256) void jac_gemm(const unsigned short* __restrict__ Amat,
                                                const unsigned short* __restrict__ Bmat,
                                                const float* __restrict__ h_kmask,
                                                const float* __restrict__ h_omask,
                                                const float* __restrict__ W3,
                                                unsigned short* __restrict__ Jout,
                                                float* __restrict__ klp_part) {
  __shared__ unsigned short Asm[128][32];
  __shared__ unsigned short Bsm[128][32];
  __shared__ float redbuf[4];

  const int s = blockIdx.x;
  const int tile = blockIdx.y;
  const int t = threadIdx.x;
  const int lane = t & 63, w = t >> 6;
  const int wm = w >> 1, wn = w & 1;
  const int lr = lane & 15, lg = lane >> 4;

  const unsigned short* Abase = (MODE == 0) ? Amat : (Amat + tile * 128 * 512);
  const unsigned short* Bbase = (MODE == 0) ? (Bmat + tile * 128 * 512)
                                            : (Bmat + (size_t)s * 65536);
  const int srow = t >> 1;
  const int kh = (t & 1) * 16;

  f32x4v acc[4][4];
#pragma unroll
  for (int a = 0; a < 4; ++a)
#pragma unroll
    for (int b = 0; b < 4; ++b) acc[a][b] = f32x4v{0.f, 0.f, 0.f, 0.f};

  for (int k0 = 0; k0 < 512; k0 += 32) {
    u16x8 av0 = *(const u16x8*)(Abase + srow * 512 + k0 + kh);
    u16x8 av1 = *(const u16x8*)(Abase + srow * 512 + k0 + kh + 8);
    u16x8 bv0 = *(const u16x8*)(Bbase + srow * 512 + k0 + kh);
    u16x8 bv1 = *(const u16x8*)(Bbase + srow * 512 + k0 + kh + 8);
    if (MODE == 0) {
      const float* mp = h_kmask + s * 512 + k0 + kh;
#pragma unroll
      for (int q = 0; q < 8; ++q) {
        if (mp[q] <= 0.f) av0[q] = 0;
        if (mp[8 + q] <= 0.f) av1[q] = 0;
      }
    }
    __syncthreads();
    *(u16x8*)&Asm[srow][kh] = av0;
    *(u16x8*)&Asm[srow][kh + 8] = av1;
    *(u16x8*)&Bsm[srow][kh] = bv0;
    *(u16x8*)&Bsm[srow][kh + 8] = bv1;
    __syncthreads();

    short8 af[4], bfv[4];
#pragma unroll
    for (int fm = 0; fm < 4; ++fm)
      af[fm] = *(const short8*)&Asm[wm * 64 + fm * 16 + lr][lg * 8];
#pragma unroll
    for (int fn = 0; fn < 4; ++fn)
      bfv[fn] = *(const short8*)&Bsm[wn * 64 + fn * 16 + lr][lg * 8];
#pragma unroll
    for (int fm = 0; fm < 4; ++fm)
#pragma unroll
      for (int fn = 0; fn < 4; ++fn)
        acc[fm][fn] = __builtin_amdgcn_mfma_f32_16x16x32_bf16(af[fm], bfv[fn],
                                                              acc[fm][fn], 0, 0, 0);
  }

  if (MODE == 0) {
#pragma unroll
    for (int fn = 0; fn < 4; ++fn) {
      int b = tile * 128 + wn * 64 + fn * 16 + lr;
      float mn = (h_omask[s * 512 + b] > 0.f) ? 1.f : 0.f;
#pragma unroll
      for (int fm = 0; fm < 4; ++fm) {
        int jbase = wm * 64 + fm * 16 + lg * 4;
#pragma unroll
        for (int r = 0; r < 4; ++r) {
          float v = acc[fm][fn][r] * mn;
          Jout[(size_t)s * 65536 + (size_t)(jbase + r) * 512 + b] = f2bf(v);
        }
      }
    }
  } else {
    float part = 0.f;
#pragma unroll
    for (int fm = 0; fm < 4; ++fm) {
#pragma unroll
      for (int r = 0; r < 4; ++r) {
        int c = tile * 128 + wm * 64 + fm * 16 + lg * 4 + r;
        float hm = h_omask[s * 512 + c];
        if (hm > 0.f) {
#pragma unroll
          for (int fn = 0; fn < 4; ++fn) {
            int j = wn * 64 + fn * 16 + lr;
            part += acc[fm][fn][r] * W3[c * 128 + j];
          }
        }
      }
    }
#pragma unroll
    for (int off = 1; off < 64; off <<= 1) part += __shfl_xor(part, off);
    if (lane == 0) redbuf[w] = part;
    __syncthreads();
    if (t == 0) klp_part[tile * 512 + s] = redbuf[0] + redbuf[1] + redbuf[2] + redbuf[3];
  }
}

// y += sum_i db[i]*ky[i];  lp += sum_i db[i]*(sum_tiles klp_part[i][tile][s])
__global__ __launch_bounds__(256) void step_update(float* __restrict__ y,
                                                   float* __restrict__ lp,
                                                   const float* __restrict__ ky,
                                                   const float* __restrict__ klp_part,
                                                   Coef6 db) {
  int i = blockIdx.x * 256 + threadIdx.x;
  if (i < 65536) {
    float a = y[i];
#pragma unroll
    for (int j = 0; j < 6; ++j) a += db.v[j] * ky[j * 65536 + i];
    y[i] = a;
  }
  if (i < 512) {
    float l = lp[i];
#pragma unroll
    for (int j = 0; j < 6; ++j) {
      const float* kp = klp_part + j * 2048;
      float tr = kp[i] + kp[512 + i] + kp[1024 + i] + kp[1536 + i];
      l += db.v[j] * tr;
    }
    lp[i] = l;
  }
}

__global__ __launch_bounds__(64) void finalize(const float* __restrict__ y,
                                               const float* __restrict__ lp,
                                               float* __restrict__ out) {
  int s = blockIdx.x, l = threadIdx.x;
  float v0 = y[s * 128 + l], v1 = y[s * 128 + 64 + l];
  float sum = v0 * v0 + v1 * v1;
#pragma unroll
  for (int off = 32; off; off >>= 1) sum += __shfl_down(sum, off);
  if (l == 0) out[s] = lp[s] + (-0.5f) * (1.8378770664093453f + sum);
}

// ---------------------------------------------------------------------------
extern "C" void kernel_launch(void* const* d_in, const int* in_sizes, int n_in,
                              void* d_out, int out_size, void* d_ws, size_t ws_size,
                              hipStream_t stream) {
  const float* y_in = (const float*)d_in[0];
  const float* Ws0 = (const float*)d_in[1];
  const float* bs0 = (const float*)d_in[2];
  const float* Ws1 = (const float*)d_in[3];
  const float* bs1 = (const float*)d_in[4];
  const float* Ws2 = (const float*)d_in[5];
  const float* bs2 = (const float*)d_in[6];
  const float* Ws3 = (const float*)d_in[7];
  const float* bs3 = (const float*)d_in[8];
  float* out = (float*)d_out;

  char* ws = (char*)d_ws;
  size_t off = 0;
  auto alloc = [&](size_t bytes) {
    void* p = ws + off;
    off = (off + bytes + 255) & ~(size_t)255;
    return p;
  };
  float* y   = (float*)alloc(65536 * 4);
  float* lp  = (float*)alloc(512 * 4);
  float* yi  = (float*)alloc(65536 * 4);
  float* h0  = (float*)alloc(262144 * 4);
  float* h1  = (float*)alloc(262144 * 4);
  float* h2  = (float*)alloc(262144 * 4);
  float* ky  = (float*)alloc(6 * 65536 * 4);
  float* klp = (float*)alloc(6 * 2048 * 4);
  unsigned short* w0y = (unsigned short*)alloc(65536 * 2);
  unsigned short* w1t = (unsigned short*)alloc(262144 * 2);
  unsigned short* w2t = (unsigned short*)alloc(262144 * 2);
  unsigned short* J1T = (unsigned short*)alloc((size_t)512 * 65536 * 2);  // 64 MiB
  (void)ws_size; (void)in_sizes; (void)n_in; (void)out_size;

  static const double DT = -0.1;
  static const double TC[6] = {0.0, 0.161, 0.327, 0.9, 0.9800255409045097, 1.0};
  static const double TA[6][5] = {
      {0, 0, 0, 0, 0},
      {0.161, 0, 0, 0, 0},
      {-0.008480655492356989, 0.335480655492357, 0, 0, 0},
      {2.8971530571054935, -6.359448489975075, 4.3622954328695815, 0, 0},
      {5.325864828439257, -11.748883564062828, 7.4955393428898365, -0.09249506636175525, 0},
      {5.86145544294642, -12.92096931784711, 8.159367898576159, -0.071584973281401,
       -0.028269050394068383}};
  static const double TB[6] = {0.09646076681806523, 0.01, 0.4798896504144996,
                               1.379008574103742, -3.290069515436081, 2.324710524099774};

  init_state<<<dim3(256), dim3(256), 0, stream>>>(y_in, y, lp);

  for (int blk = 0; blk < 2; ++blk) {
    const float* W0 = Ws0 + blk * 129 * 512;
    const float* b0 = bs0 + blk * 512;
    const float* W1 = Ws1 + blk * 262144;
    const float* b1 = bs1 + blk * 512;
    const float* W2 = Ws2 + blk * 262144;
    const float* b2 = bs2 + blk * 512;
    const float* W3 = Ws3 + blk * 65536;
    const float* b3 = bs3 + blk * 128;

    cast_weights<<<dim3(2304), dim3(256), 0, stream>>>(W0, W1, W2, w0y, w1t, w2t);

    for (int n = 0; n < 10; ++n) {
      float t = 1.0f + (-0.1f) * (float)n;
      for (int i = 0; i < 6; ++i) {
        float ti = t + (float)(TC[i] * DT);
        Coef5 ca;
        for (int j = 0; j < 5; ++j) ca.v[j] = (j < i) ? (float)(DT * TA[i][j]) : 0.f;

        prep_stage<<<dim3(256), dim3(256), 0, stream>>>(y, ky, yi, klp + i * 2048, ca, i);
        fwd_gemm<true, true><<<dim3(8, 8), 256, 0, stream>>>(yi, W0 + 512, b0, W0, ti,
                                                             h0, 512, 512, 128);
        fwd_gemm<true, false><<<dim3(8, 8), 256, 0, stream>>>(h0, W1, b1, nullptr, 0.f,
                                                              h1, 512, 512, 512);
        fwd_gemm<true, false><<<dim3(8, 8), 256, 0, stream>>>(h1, W2, b2, nullptr, 0.f,
                                                              h2, 512, 512, 512);
        fwd_gemm<false, false><<<dim3(2, 8), 256, 0, stream>>>(h2, W3, b3, nullptr, 0.f,
                                                               ky + i * 65536, 512, 128, 512);
        jac_gemm<0><<<dim3(512, 4), 256, 0, stream>>>(w0y, w1t, h0, h1, nullptr, J1T,
                                                      nullptr);
        jac_gemm<1><<<dim3(512, 4), 256, 0, stream>>>(w2t, J1T, nullptr, h2, W3, nullptr,
                                                      klp + i * 2048);
      }
      Coef6 db;
      for (int i2 = 0; i2 < 6; ++i2) db.v[i2] = (float)(DT * TB[i2]);
      step_update<<<dim3(256), dim3(256), 0, stream>>>(y, lp, ky, klp, db);
    }
  }
  finalize<<<dim3(512), dim3(64), 0, stream>>>(y, lp, out);
}

// Round 2
// 23092.397 us; speedup vs baseline: 1.2317x; 1.2317x over previous
//
#include <hip/hip_runtime.h>

// ---------------------------------------------------------------------------
// CNF forward: 2 blocks x Tsit5(10 steps x 6 stages).
// Per stage: f32 forward MLP (512x[129-512-512-512-128]) + exact Jacobian
// trace via bf16 MFMA propagation, batched over 512 samples.
// Round 2: jac kernels rebuilt with global_load_lds(16B) staging, XOR-swizzled
// LDS (pre-swizzled global source), fragment-AND masking, packed 8B J1T
// stores; prep_stage fused into fwd L0; u16 masks from fwd epilogues.
// ---------------------------------------------------------------------------

using short8 = __attribute__((ext_vector_type(8))) short;
using u16x8  = __attribute__((ext_vector_type(8))) unsigned short;
using f32x4v = __attribute__((ext_vector_type(4))) float;

__device__ __forceinline__ unsigned short f2bf(float f) {
  union { float f; unsigned u; } v; v.f = f;
  unsigned r = v.u + 0x7fffu + ((v.u >> 16) & 1u);
  return (unsigned short)(r >> 16);
}

typedef const __attribute__((address_space(1))) void gas_t;
typedef __attribute__((address_space(3))) void las_t;
__device__ __forceinline__ void gl_lds16(const void* g, void* l) {
  __builtin_amdgcn_global_load_lds((gas_t*)g, (las_t*)l, 16, 0, 0);
}

struct Coef5 { float v[5]; };
struct Coef6 { float v[6]; };

// ---------------------------------------------------------------------------
__global__ __launch_bounds__(256) void init_state(const float* __restrict__ y_in,
                                                  float* __restrict__ y,
                                                  float* __restrict__ lp) {
  int i = blockIdx.x * 256 + threadIdx.x;
  if (i < 512 * 128) y[i] = y_in[i];
  if (i < 512) lp[i] = 0.f;
}

// w0y[j][a] = bf16(W0[1+j][a]) (128x512); w1t[b][a] = bf16(W1[a][b]);
// w2t[c][b] = bf16(W2[b][c])   (512x512 each)
__global__ __launch_bounds__(256) void cast_weights(const float* __restrict__ W0,
                                                    const float* __restrict__ W1,
                                                    const float* __restrict__ W2,
                                                    unsigned short* __restrict__ w0y,
                                                    unsigned short* __restrict__ w1t,
                                                    unsigned short* __restrict__ w2t) {
  int i = blockIdx.x * 256 + threadIdx.x;
  if (i < 65536) {
    int j = i >> 9, a = i & 511;
    w0y[i] = f2bf(W0[(1 + j) * 512 + a]);
  } else if (i < 65536 + 262144) {
    int k = i - 65536; int b = k >> 9, a = k & 511;
    w1t[k] = f2bf(W1[a * 512 + b]);
  } else if (i < 65536 + 2 * 262144) {
    int k = i - 65536 - 262144; int c = k >> 9, b = k & 511;
    w2t[k] = f2bf(W2[b * 512 + c]);
  }
}

// f32 SIMT GEMM: C[M,N] = act(A[M,K] @ W[K,N] + bias (+ t*wrow0 if L0)).
// L0 also fuses yi = y + sum c[j]*ky[j] on the A-load path. RELU layers write
// a u16 mask (0xFFFF where active).
template <bool RELU, bool L0>
__global__ __launch_bounds__(256) void fwd_gemm(const float* __restrict__ A,
                                                const float* __restrict__ kyb,
                                                const float* __restrict__ W,
                                                const float* __restrict__ bias,
                                                const float* __restrict__ wrow0,
                                                float tval, Coef5 ca, int nc,
                                                float* __restrict__ C,
                                                unsigned short* __restrict__ mout,
                                                int M, int N, int K) {
  __shared__ float As[64][20];
  __shared__ float Bs[16][64];
  const int tx = threadIdx.x & 15, ty = threadIdx.x >> 4;
  const int m0 = blockIdx.y * 64, n0 = blockIdx.x * 64;
  float acc[4][4] = {};
  const int ai = threadIdx.x * 4;
  const int am = ai >> 4, ak = ai & 15;
  const int bk = threadIdx.x >> 4, bn = (threadIdx.x & 15) * 4;
  for (int k0 = 0; k0 < K; k0 += 16) {
    float4 av;
    if (L0) {
      int idx = (m0 + am) * 128 + k0 + ak;
      av = *(const float4*)&A[idx];
      for (int j2 = 0; j2 < nc; ++j2) {
        float4 kv = *(const float4*)&kyb[j2 * 65536 + idx];
        av.x += ca.v[j2] * kv.x; av.y += ca.v[j2] * kv.y;
        av.z += ca.v[j2] * kv.z; av.w += ca.v[j2] * kv.w;
      }
    } else {
      av = *(const float4*)&A[(m0 + am) * K + k0 + ak];
    }
    float4 bv = *(const float4*)&W[(k0 + bk) * N + n0 + bn];
    __syncthreads();
    *(float4*)&As[am][ak] = av;
    *(float4*)&Bs[bk][bn] = bv;
    __syncthreads();
#pragma unroll
    for (int k = 0; k < 16; ++k) {
      float a[4], b[4];
#pragma unroll
      for (int r = 0; r < 4; ++r) a[r] = As[ty * 4 + r][k];
#pragma unroll
      for (int cc = 0; cc < 4; ++cc) b[cc] = Bs[k][tx * 4 + cc];
#pragma unroll
      for (int r = 0; r < 4; ++r)
#pragma unroll
        for (int cc = 0; cc < 4; ++cc) acc[r][cc] = fmaf(a[r], b[cc], acc[r][cc]);
    }
  }
#pragma unroll
  for (int r = 0; r < 4; ++r) {
    int m = m0 + ty * 4 + r;
    float ov[4];
#pragma unroll
    for (int cc = 0; cc < 4; ++cc) {
      int n = n0 + tx * 4 + cc;
      float be = bias[n];
      if (L0) be = fmaf(tval, wrow0[n], be);
      float v = acc[r][cc] + be;
      if (RELU) v = fmaxf(v, 0.f);
      ov[cc] = v;
    }
    *(float4*)&C[m * N + n0 + tx * 4] = *(float4*)ov;
    if (RELU && mout) {
      ushort4 mo;
      mo.x = ov[0] > 0.f ? 0xFFFFu : 0u;
      mo.y = ov[1] > 0.f ? 0xFFFFu : 0u;
      mo.z = ov[2] > 0.f ? 0xFFFFu : 0u;
      mo.w = ov[3] > 0.f ? 0xFFFFu : 0u;
      *(ushort4*)&mout[m * 512 + n0 + tx * 4] = mo;
    }
  }
}

// ---------------------------------------------------------------------------
// Jacobian MFMA GEMMs, 128x128 tile, 4 waves (2x2), BK=64, K=512,
// global_load_lds(16B) staging with XOR-swizzled source, swizzled ds_read.
//
// MODE 0 (jacA): J1[b][j] = D1[b] * sum_a w1t[b][a] * (D0[a]*w0y[j][a])
//   A = w1t rows b (tile), B = w0y rows j, D0 as fragment-AND (u16 mask in
//   LDS), D1 + bf16 pack in epilogue -> J1T[s][j][b] (8B packed stores).
// MODE 1 (jacB): T[c][j] = sum_b w2t[c][b] * J1[b][j];
//   klp[tile][s] = sum_{c in tile, j} D2[c] * W3[c][j] * T[c][j]
// ---------------------------------------------------------------------------
template <int MODE>
__global__ __launch_bounds__(256, 3) void jac_k(const unsigned short* __restrict__ Am,
                                                const unsigned short* __restrict__ Bm,
                                                const unsigned short* __restrict__ kmask,
                                                const unsigned short* __restrict__ omask,
                                                const float* __restrict__ W3,
                                                unsigned short* __restrict__ Jout,
                                                float* __restrict__ klp) {
  __shared__ unsigned short As[128 * 64];
  __shared__ unsigned short Bs[128 * 64];
  __shared__ unsigned short Ms[512];
  __shared__ float red[4];

  const int s = blockIdx.x, tl = blockIdx.y;
  const int t = threadIdx.x, l = t & 63, w = t >> 6;
  const int wm = w >> 1, wn = w & 1;
  const int lr = l & 15, lg = l >> 4;
  const int rc = l >> 3;                       // row within an 8-row chunk
  const int swz8 = ((l & 7) ^ (rc & 7)) * 8;   // pre-swizzled k-slot (elems)

  const unsigned short* Bbase = (MODE == 0) ? Bm : (Bm + (size_t)s * 65536);
  const unsigned short* aRow = Am + (size_t)(tl * 128 + rc) * 512 + swz8;
  const unsigned short* bRow = Bbase + (size_t)rc * 512 + swz8;

  if (MODE == 0 && w == 0) gl_lds16(kmask + s * 512 + l * 8, (void*)Ms);

  f32x4v acc[4][4];
#pragma unroll
  for (int a = 0; a < 4; ++a)
#pragma unroll
    for (int b = 0; b < 4; ++b) acc[a][b] = f32x4v{0.f, 0.f, 0.f, 0.f};

  for (int k0 = 0; k0 < 512; k0 += 64) {
    __syncthreads();  // previous iter's readers done
#pragma unroll
    for (int i = 0; i < 4; ++i) {
      int q = i * 4 + w;
      gl_lds16(aRow + q * 4096 + k0, (char*)As + q * 1024);
      gl_lds16(bRow + q * 4096 + k0, (char*)Bs + q * 1024);
    }
    __syncthreads();  // implicit vmcnt(0) drain -> tiles ready
#pragma unroll
    for (int ks = 0; ks < 2; ++ks) {
      const int slot = ((ks * 4 + lg) ^ (lr & 7)) << 4;  // byte offset in row
      u16x8 mv;
      if (MODE == 0) mv = *(const u16x8*)&Ms[k0 + ks * 32 + lg * 8];
      short8 af[4], bfv[4];
#pragma unroll
      for (int fm = 0; fm < 4; ++fm)
        af[fm] = *(const short8*)((const char*)As + ((wm * 64 + fm * 16 + lr) << 7) + slot);
#pragma unroll
      for (int fn = 0; fn < 4; ++fn) {
        u16x8 bv = *(const u16x8*)((const char*)Bs + ((wn * 64 + fn * 16 + lr) << 7) + slot);
        if (MODE == 0) bv &= mv;
        bfv[fn] = (short8)bv;
      }
#pragma unroll
      for (int fm = 0; fm < 4; ++fm)
#pragma unroll
        for (int fn = 0; fn < 4; ++fn)
          acc[fm][fn] = __builtin_amdgcn_mfma_f32_16x16x32_bf16(af[fm], bfv[fn],
                                                                acc[fm][fn], 0, 0, 0);
    }
  }

  if (MODE == 0) {
#pragma unroll
    for (int fm = 0; fm < 4; ++fm) {
      int bb = tl * 128 + wm * 64 + fm * 16 + lg * 4;
      ushort4 m4 = *(const ushort4*)&omask[s * 512 + bb];
#pragma unroll
      for (int fn = 0; fn < 4; ++fn) {
        int j = wn * 64 + fn * 16 + lr;
        ushort4 o;
        o.x = m4.x ? f2bf(acc[fm][fn][0]) : (unsigned short)0;
        o.y = m4.y ? f2bf(acc[fm][fn][1]) : (unsigned short)0;
        o.z = m4.z ? f2bf(acc[fm][fn][2]) : (unsigned short)0;
        o.w = m4.w ? f2bf(acc[fm][fn][3]) : (unsigned short)0;
        *(ushort4*)&Jout[(size_t)s * 65536 + (size_t)j * 512 + bb] = o;
      }
    }
  } else {
    float part = 0.f;
#pragma unroll
    for (int fm = 0; fm < 4; ++fm) {
      int cb = tl * 128 + wm * 64 + fm * 16 + lg * 4;
      ushort4 m4 = *(const ushort4*)&omask[s * 512 + cb];
      unsigned short mm[4] = {m4.x, m4.y, m4.z, m4.w};
#pragma unroll
      for (int r = 0; r < 4; ++r) {
        if (mm[r]) {
          const float* w3r = W3 + (cb + r) * 128 + wn * 64;
#pragma unroll
          for (int fn = 0; fn < 4; ++fn) part += acc[fm][fn][r] * w3r[fn * 16 + lr];
        }
      }
    }
#pragma unroll
    for (int off = 1; off < 64; off <<= 1) part += __shfl_xor(part, off);
    if (l == 0) red[w] = part;
    __syncthreads();
    if (t == 0) klp[tl * 512 + s] = red[0] + red[1] + red[2] + red[3];
  }
}

// y += sum_i db[i]*ky[i];  lp += sum_i db[i]*(sum_tiles klp[i][tile][s])
__global__ __launch_bounds__(256) void step_update(float* __restrict__ y,
                                                   float* __restrict__ lp,
                                                   const float* __restrict__ ky,
                                                   const float* __restrict__ klp_part,
                                                   Coef6 db) {
  int i = blockIdx.x * 256 + threadIdx.x;
  if (i < 65536) {
    float a = y[i];
#pragma unroll
    for (int j = 0; j < 6; ++j) a += db.v[j] * ky[j * 65536 + i];
    y[i] = a;
  }
  if (i < 512) {
    float l = lp[i];
#pragma unroll
    for (int j = 0; j < 6; ++j) {
      const float* kp = klp_part + j * 2048;
      float tr = kp[i] + kp[512 + i] + kp[1024 + i] + kp[1536 + i];
      l += db.v[j] * tr;
    }
    lp[i] = l;
  }
}

__global__ __launch_bounds__(64) void finalize(const float* __restrict__ y,
                                               const float* __restrict__ lp,
                                               float* __restrict__ out) {
  int s = blockIdx.x, l = threadIdx.x;
  float v0 = y[s * 128 + l], v1 = y[s * 128 + 64 + l];
  float sum = v0 * v0 + v1 * v1;
#pragma unroll
  for (int off = 32; off; off >>= 1) sum += __shfl_down(sum, off);
  if (l == 0) out[s] = lp[s] + (-0.5f) * (1.8378770664093453f + sum);
}

// ---------------------------------------------------------------------------
extern "C" void kernel_launch(void* const* d_in, const int* in_sizes, int n_in,
                              void* d_out, int out_size, void* d_ws, size_t ws_size,
                              hipStream_t stream) {
  const float* y_in = (const float*)d_in[0];
  const float* Ws0 = (const float*)d_in[1];
  const float* bs0 = (const float*)d_in[2];
  const float* Ws1 = (const float*)d_in[3];
  const float* bs1 = (const float*)d_in[4];
  const float* Ws2 = (const float*)d_in[5];
  const float* bs2 = (const float*)d_in[6];
  const float* Ws3 = (const float*)d_in[7];
  const float* bs3 = (const float*)d_in[8];
  float* out = (float*)d_out;

  char* ws = (char*)d_ws;
  size_t off = 0;
  auto alloc = [&](size_t bytes) {
    void* p = ws + off;
    off = (off + bytes + 255) & ~(size_t)255;
    return p;
  };
  float* y   = (float*)alloc(65536 * 4);
  float* lp  = (float*)alloc(512 * 4);
  float* h0  = (float*)alloc(262144 * 4);
  float* h1  = (float*)alloc(262144 * 4);
  float* h2  = (float*)alloc(262144 * 4);
  float* ky  = (float*)alloc(6 * 65536 * 4);
  float* klp = (float*)alloc(6 * 2048 * 4);
  unsigned short* mask0 = (unsigned short*)alloc(262144 * 2);
  unsigned short* mask1 = (unsigned short*)alloc(262144 * 2);
  unsigned short* mask2 = (unsigned short*)alloc(262144 * 2);
  unsigned short* w0y = (unsigned short*)alloc(65536 * 2);
  unsigned short* w1t = (unsigned short*)alloc(262144 * 2);
  unsigned short* w2t = (unsigned short*)alloc(262144 * 2);
  unsigned short* J1T = (unsigned short*)alloc((size_t)512 * 65536 * 2);  // 64 MiB
  (void)ws_size; (void)in_sizes; (void)n_in; (void)out_size;

  static const double DT = -0.1;
  static const double TC[6] = {0.0, 0.161, 0.327, 0.9, 0.9800255409045097, 1.0};
  static const double TA[6][5] = {
      {0, 0, 0, 0, 0},
      {0.161, 0, 0, 0, 0},
      {-0.008480655492356989, 0.335480655492357, 0, 0, 0},
      {2.8971530571054935, -6.359448489975075, 4.3622954328695815, 0, 0},
      {5.325864828439257, -11.748883564062828, 7.4955393428898365, -0.09249506636175525, 0},
      {5.86145544294642, -12.92096931784711, 8.159367898576159, -0.071584973281401,
       -0.028269050394068383}};
  static const double TB[6] = {0.09646076681806523, 0.01, 0.4798896504144996,
                               1.379008574103742, -3.290069515436081, 2.324710524099774};

  init_state<<<dim3(256), dim3(256), 0, stream>>>(y_in, y, lp);

  for (int blk = 0; blk < 2; ++blk) {
    const float* W0 = Ws0 + blk * 129 * 512;
    const float* b0 = bs0 + blk * 512;
    const float* W1 = Ws1 + blk * 262144;
    const float* b1 = bs1 + blk * 512;
    const float* W2 = Ws2 + blk * 262144;
    const float* b2 = bs2 + blk * 512;
    const float* W3 = Ws3 + blk * 65536;
    const float* b3 = bs3 + blk * 128;

    cast_weights<<<dim3(2304), dim3(256), 0, stream>>>(W0, W1, W2, w0y, w1t, w2t);

    for (int n = 0; n < 10; ++n) {
      float t = 1.0f + (-0.1f) * (float)n;
      for (int i = 0; i < 6; ++i) {
        float ti = t + (float)(TC[i] * DT);
        Coef5 ca;
        for (int j = 0; j < 5; ++j) ca.v[j] = (j < i) ? (float)(DT * TA[i][j]) : 0.f;

        fwd_gemm<true, true><<<dim3(8, 8), 256, 0, stream>>>(
            y, ky, W0 + 512, b0, W0, ti, ca, i, h0, mask0, 512, 512, 128);
        fwd_gemm<true, false><<<dim3(8, 8), 256, 0, stream>>>(
            h0, nullptr, W1, b1, nullptr, 0.f, ca, 0, h1, mask1, 512, 512, 512);
        fwd_gemm<true, false><<<dim3(8, 8), 256, 0, stream>>>(
            h1, nullptr, W2, b2, nullptr, 0.f, ca, 0, h2, mask2, 512, 512, 512);
        fwd_gemm<false, false><<<dim3(2, 8), 256, 0, stream>>>(
            h2, nullptr, W3, b3, nullptr, 0.f, ca, 0, ky + i * 65536, nullptr,
            512, 128, 512);
        jac_k<0><<<dim3(512, 4), 256, 0, stream>>>(w1t, w0y, mask0, mask1, nullptr,
                                                   J1T, nullptr);
        jac_k<1><<<dim3(512, 4), 256, 0, stream>>>(w2t, J1T, nullptr, mask2, W3,
                                                   nullptr, klp + i * 2048);
      }
      Coef6 db;
      for (int i2 = 0; i2 < 6; ++i2) db.v[i2] = (float)(DT * TB[i2]);
      step_update<<<dim3(256), dim3(256), 0, stream>>>(y, lp, ky, klp, db);
    }
  }
  finalize<<<dim3(512), dim3(64), 0, stream>>>(y, lp, out);
}

// Round 3
// 16298.997 us; speedup vs baseline: 1.7451x; 1.4168x over previous
//
#include <hip/hip_runtime.h>

// ---------------------------------------------------------------------------
// CNF forward: 2 blocks x Tsit5(10 steps x 6 stages).
// Round 3:
//  - fwd MLP -> split-bf16 (hi+lo) MFMA, activations stored as hi/lo pairs,
//    masks implicit (hi != 0), weights pre-split+transposed in cast_weights.
//  - jac kernels: 256x128 tile, wave tile 128x64 (42.7 FLOP/B), grid (2,512);
//    halves J1T re-read traffic.
// ---------------------------------------------------------------------------

using short8 = __attribute__((ext_vector_type(8))) short;
using u16x8  = __attribute__((ext_vector_type(8))) unsigned short;
using f32x4v = __attribute__((ext_vector_type(4))) float;

__device__ __forceinline__ unsigned short f2bf(float f) {
  union { float f; unsigned u; } v; v.f = f;
  unsigned r = v.u + 0x7fffu + ((v.u >> 16) & 1u);
  return (unsigned short)(r >> 16);
}
__device__ __forceinline__ float bf2f(unsigned short h) {
  union { unsigned u; float f; } v; v.u = ((unsigned)h) << 16; return v.f;
}

typedef const __attribute__((address_space(1))) void gas_t;
typedef __attribute__((address_space(3))) void las_t;
__device__ __forceinline__ void gl_lds16(const void* g, void* l) {
  __builtin_amdgcn_global_load_lds((gas_t*)g, (las_t*)l, 16, 0, 0);
}

struct Coef5 { float v[5]; };
struct Coef6 { float v[6]; };

// ---------------------------------------------------------------------------
__global__ __launch_bounds__(256) void init_state(const float* __restrict__ y_in,
                                                  float* __restrict__ y,
                                                  float* __restrict__ lp) {
  int i = blockIdx.x * 256 + threadIdx.x;
  if (i < 512 * 128) y[i] = y_in[i];
  if (i < 512) lp[i] = 0.f;
}

// Weight prep (per block):
//  w0y[j][a]  = bf16(W0[1+j][a])              (128x512, jac hi only)
//  w0t[n][k]  = split(W0[1+k][n])             (512x128)
//  w1t[b][a]  = split(W1[a][b])               (512x512; hi shared with jac)
//  w2t[c][b]  = split(W2[b][c])               (512x512; hi shared with jac)
//  w3t[j][c]  = split(W3[c][j])               (128x512)
__global__ __launch_bounds__(256) void cast_weights(
    const float* __restrict__ W0, const float* __restrict__ W1,
    const float* __restrict__ W2, const float* __restrict__ W3,
    unsigned short* __restrict__ w0y,
    unsigned short* __restrict__ w0tH, unsigned short* __restrict__ w0tL,
    unsigned short* __restrict__ w1tH, unsigned short* __restrict__ w1tL,
    unsigned short* __restrict__ w2tH, unsigned short* __restrict__ w2tL,
    unsigned short* __restrict__ w3tH, unsigned short* __restrict__ w3tL) {
  int i = blockIdx.x * 256 + threadIdx.x;
  if (i < 65536) {
    int j = i >> 9, a = i & 511;
    w0y[i] = f2bf(W0[(1 + j) * 512 + a]);
    return;
  }
  i -= 65536;
  float v;
  unsigned short* dh;
  unsigned short* dl;
  int di;
  if (i < 65536) {
    int n = i >> 7, k = i & 127;
    v = W0[(1 + k) * 512 + n]; dh = w0tH; dl = w0tL; di = i;
  } else if (i < 65536 + 262144) {
    int q = i - 65536; int n = q >> 9, k = q & 511;
    v = W1[k * 512 + n]; dh = w1tH; dl = w1tL; di = q;
  } else if (i < 65536 + 2 * 262144) {
    int q = i - 65536 - 262144; int c = q >> 9, b = q & 511;
    v = W2[b * 512 + c]; dh = w2tH; dl = w2tL; di = q;
  } else if (i < 2 * 65536 + 2 * 262144) {
    int q = i - 65536 - 2 * 262144; int j = q >> 9, c = q & 511;
    v = W3[c * 128 + j]; dh = w3tH; dl = w3tL; di = q;
  } else {
    return;
  }
  unsigned short hi = f2bf(v);
  dh[di] = hi;
  dl[di] = f2bf(v - bf2f(hi));
}

// ---------------------------------------------------------------------------
// fwd split-bf16 MFMA GEMM: C[M,N] = act(A @ W + bias (+ t*wrow0 if L0)).
// Tile 64x64, BK=32, 4 waves (2x2), wave 32x32, 2x2 16x16x32 frags.
// A,B staged as hi/lo bf16 into XOR-granule-swizzled linear LDS.
// L0: A = y + sum ca*ky built in-register, split on the fly (K=128).
// RELU layers store hi/lo pairs of h (mask implicit: hi != 0).
// ---------------------------------------------------------------------------
template <bool RELU, bool L0>
__global__ __launch_bounds__(256) void fwd_mfma(
    const float* __restrict__ yb, const float* __restrict__ kyb,
    const unsigned short* __restrict__ Ahi, const unsigned short* __restrict__ Alo,
    const unsigned short* __restrict__ WtH, const unsigned short* __restrict__ WtL,
    const float* __restrict__ bias, const float* __restrict__ wrow0,
    float tval, Coef5 ca, int nc,
    float* __restrict__ Cf, unsigned short* __restrict__ Hhi,
    unsigned short* __restrict__ Hlo, int N, int K) {
  __shared__ unsigned short AsH[2048], AsL[2048], BsH[2048], BsL[2048];
  const int t = threadIdx.x, l = t & 63, w = t >> 6;
  const int wm = w >> 1, wn = w & 1;
  const int lr = l & 15, lg = l >> 4;
  const int m0 = blockIdx.y * 64, n0 = blockIdx.x * 64;
  // gl_lds16 lane map: 1024B chunk = 16 rows x 64B; XOR-presw granule source.
  const int grow = l >> 2;
  const int gsw = ((l & 3) ^ (grow & 3)) * 8;
  const unsigned short* bH = WtH + (size_t)(n0 + w * 16 + grow) * K + gsw;
  const unsigned short* bL = WtL + (size_t)(n0 + w * 16 + grow) * K + gsw;
  const unsigned short* aH = nullptr;
  const unsigned short* aL = nullptr;
  if (!L0) {
    aH = Ahi + (size_t)(m0 + w * 16 + grow) * K + gsw;
    aL = Alo + (size_t)(m0 + w * 16 + grow) * K + gsw;
  }

  f32x4v acc[2][2];
#pragma unroll
  for (int a = 0; a < 2; ++a)
#pragma unroll
    for (int b = 0; b < 2; ++b) acc[a][b] = f32x4v{0.f, 0.f, 0.f, 0.f};

  for (int k0 = 0; k0 < K; k0 += 32) {
    __syncthreads();
    if (L0) {
      const int row = t >> 2, e8 = (t & 3) * 8;
      const int gidx = (m0 + row) * 128 + k0 + e8;
      float x[8];
      *(float4*)&x[0] = *(const float4*)&yb[gidx];
      *(float4*)&x[4] = *(const float4*)&yb[gidx + 4];
      for (int j2 = 0; j2 < nc; ++j2) {
        float4 u0 = *(const float4*)&kyb[j2 * 65536 + gidx];
        float4 u1 = *(const float4*)&kyb[j2 * 65536 + gidx + 4];
        x[0] = fmaf(ca.v[j2], u0.x, x[0]); x[1] = fmaf(ca.v[j2], u0.y, x[1]);
        x[2] = fmaf(ca.v[j2], u0.z, x[2]); x[3] = fmaf(ca.v[j2], u0.w, x[3]);
        x[4] = fmaf(ca.v[j2], u1.x, x[4]); x[5] = fmaf(ca.v[j2], u1.y, x[5]);
        x[6] = fmaf(ca.v[j2], u1.z, x[6]); x[7] = fmaf(ca.v[j2], u1.w, x[7]);
      }
      u16x8 hi8, lo8;
#pragma unroll
      for (int e = 0; e < 8; ++e) {
        unsigned short h = f2bf(x[e]);
        hi8[e] = h;
        lo8[e] = f2bf(x[e] - bf2f(h));
      }
      const int wb = row * 64 + (((t & 3) ^ (row & 3)) << 4);
      *(u16x8*)((char*)AsH + wb) = hi8;
      *(u16x8*)((char*)AsL + wb) = lo8;
    } else {
      gl_lds16(aH + k0, (char*)AsH + w * 1024);
      gl_lds16(aL + k0, (char*)AsL + w * 1024);
    }
    gl_lds16(bH + k0, (char*)BsH + w * 1024);
    gl_lds16(bL + k0, (char*)BsL + w * 1024);
    __syncthreads();

    short8 ah[2], al[2], bh2[2], bl2[2];
#pragma unroll
    for (int fm = 0; fm < 2; ++fm) {
      int row = wm * 32 + fm * 16 + lr;
      int byo = row * 64 + ((lg ^ (lr & 3)) << 4);
      ah[fm] = *(const short8*)((const char*)AsH + byo);
      al[fm] = *(const short8*)((const char*)AsL + byo);
    }
#pragma unroll
    for (int fn = 0; fn < 2; ++fn) {
      int row = wn * 32 + fn * 16 + lr;
      int byo = row * 64 + ((lg ^ (lr & 3)) << 4);
      bh2[fn] = *(const short8*)((const char*)BsH + byo);
      bl2[fn] = *(const short8*)((const char*)BsL + byo);
    }
#pragma unroll
    for (int fm = 0; fm < 2; ++fm)
#pragma unroll
      for (int fn = 0; fn < 2; ++fn) {
        acc[fm][fn] = __builtin_amdgcn_mfma_f32_16x16x32_bf16(ah[fm], bh2[fn],
                                                              acc[fm][fn], 0, 0, 0);
        acc[fm][fn] = __builtin_amdgcn_mfma_f32_16x16x32_bf16(ah[fm], bl2[fn],
                                                              acc[fm][fn], 0, 0, 0);
        acc[fm][fn] = __builtin_amdgcn_mfma_f32_16x16x32_bf16(al[fm], bh2[fn],
                                                              acc[fm][fn], 0, 0, 0);
      }
  }

#pragma unroll
  for (int fm = 0; fm < 2; ++fm)
#pragma unroll
    for (int fn = 0; fn < 2; ++fn) {
      int n = n0 + wn * 32 + fn * 16 + lr;
      float be = bias[n];
      if (L0) be = fmaf(tval, wrow0[n], be);
#pragma unroll
      for (int r = 0; r < 4; ++r) {
        int m = m0 + wm * 32 + fm * 16 + lg * 4 + r;
        float v = acc[fm][fn][r] + be;
        if (RELU) {
          v = fmaxf(v, 0.f);
          unsigned short h = f2bf(v);
          Hhi[m * N + n] = h;
          Hlo[m * N + n] = f2bf(v - bf2f(h));
        } else {
          Cf[m * N + n] = v;
        }
      }
    }
}

// ---------------------------------------------------------------------------
// Jacobian MFMA GEMMs. Tile 256(M)x128(N), 4 waves (2x2), wave 128x64, BK=64,
// K=512. global_load_lds(16B) staging, XOR-swizzled source + swizzled ds_read.
// Masks come from activation hi-buffers (bf16 bits != 0  <=>  h > 0).
//
// MODE 0 (jacA): J1[b][j] = D1[b] * sum_a w1t[b][a] * (D0[a]*w0y[j][a])
//   A = w1t rows b (256-tile), B = w0y rows j, D0 via fragment zero-select,
//   D1 + bf16 pack in epilogue -> J1T[s][j][b] (8B packed stores).
// MODE 1 (jacB): T[c][j] = sum_b w2t[c][b] * J1[b][j];
//   klp[tile][s] = sum_{c in tile, j} D2[c] * W3[c][j] * T[c][j]
// ---------------------------------------------------------------------------
template <int MODE>
__global__ __launch_bounds__(256, 2) void jac_k(const unsigned short* __restrict__ Am,
                                                const unsigned short* __restrict__ Bm,
                                                const unsigned short* __restrict__ kmaskH,
                                                const unsigned short* __restrict__ omaskH,
                                                const float* __restrict__ W3,
                                                unsigned short* __restrict__ Jout,
                                                float* __restrict__ klp) {
  __shared__ unsigned short As[256 * 64];  // 32 KB
  __shared__ unsigned short Bs[128 * 64];  // 16 KB
  __shared__ unsigned short Ms[512];
  __shared__ float red[4];

  const int tl = blockIdx.x, s = blockIdx.y;
  const int t = threadIdx.x, l = t & 63, w = t >> 6;
  const int wm = w >> 1, wn = w & 1;
  const int lr = l & 15, lg = l >> 4;
  const int rc = l >> 3;
  const int swz8 = ((l & 7) ^ rc) * 8;

  const unsigned short* Bbase = (MODE == 0) ? Bm : (Bm + (size_t)s * 65536);
  const unsigned short* aRow = Am + (size_t)(tl * 256 + rc) * 512 + swz8;
  const unsigned short* bRow = Bbase + (size_t)rc * 512 + swz8;

  if (MODE == 0 && w == 0) gl_lds16(kmaskH + s * 512 + l * 8, (void*)Ms);

  f32x4v acc[8][4];
#pragma unroll
  for (int a = 0; a < 8; ++a)
#pragma unroll
    for (int b = 0; b < 4; ++b) acc[a][b] = f32x4v{0.f, 0.f, 0.f, 0.f};

  for (int k0 = 0; k0 < 512; k0 += 64) {
    __syncthreads();
#pragma unroll
    for (int i = 0; i < 8; ++i) {
      int q = i * 4 + w;
      gl_lds16(aRow + (size_t)q * 4096 + k0, (char*)As + q * 1024);
    }
#pragma unroll
    for (int i = 0; i < 4; ++i) {
      int q = i * 4 + w;
      gl_lds16(bRow + (size_t)q * 4096 + k0, (char*)Bs + q * 1024);
    }
    __syncthreads();
#pragma unroll
    for (int ks = 0; ks < 2; ++ks) {
      const int slot = ((ks * 4 + lg) ^ (lr & 7)) << 4;
      u16x8 mv;
      if (MODE == 0) mv = *(const u16x8*)&Ms[k0 + ks * 32 + lg * 8];
      short8 af[8], bfv[4];
#pragma unroll
      for (int fm = 0; fm < 8; ++fm)
        af[fm] = *(const short8*)((const char*)As + ((wm * 128 + fm * 16 + lr) << 7) + slot);
#pragma unroll
      for (int fn = 0; fn < 4; ++fn) {
        u16x8 bv = *(const u16x8*)((const char*)Bs + ((wn * 64 + fn * 16 + lr) << 7) + slot);
        if (MODE == 0) {
#pragma unroll
          for (int q = 0; q < 8; ++q)
            if (mv[q] == 0) bv[q] = 0;
        }
        bfv[fn] = (short8)bv;
      }
#pragma unroll
      for (int fm = 0; fm < 8; ++fm)
#pragma unroll
        for (int fn = 0; fn < 4; ++fn)
          acc[fm][fn] = __builtin_amdgcn_mfma_f32_16x16x32_bf16(af[fm], bfv[fn],
                                                                acc[fm][fn], 0, 0, 0);
    }
  }

  if (MODE == 0) {
#pragma unroll
    for (int fm = 0; fm < 8; ++fm) {
      int bb = tl * 256 + wm * 128 + fm * 16 + lg * 4;
      ushort4 m4 = *(const ushort4*)&omaskH[s * 512 + bb];
#pragma unroll
      for (int fn = 0; fn < 4; ++fn) {
        int j = wn * 64 + fn * 16 + lr;
        ushort4 o;
        o.x = m4.x ? f2bf(acc[fm][fn][0]) : (unsigned short)0;
        o.y = m4.y ? f2bf(acc[fm][fn][1]) : (unsigned short)0;
        o.z = m4.z ? f2bf(acc[fm][fn][2]) : (unsigned short)0;
        o.w = m4.w ? f2bf(acc[fm][fn][3]) : (unsigned short)0;
        *(ushort4*)&Jout[(size_t)s * 65536 + (size_t)j * 512 + bb] = o;
      }
    }
  } else {
    float part = 0.f;
#pragma unroll
    for (int fm = 0; fm < 8; ++fm) {
      int cb = tl * 256 + wm * 128 + fm * 16 + lg * 4;
      ushort4 m4 = *(const ushort4*)&omaskH[s * 512 + cb];
      unsigned short mm[4] = {m4.x, m4.y, m4.z, m4.w};
#pragma unroll
      for (int r = 0; r < 4; ++r) {
        if (mm[r]) {
          const float* w3r = W3 + (cb + r) * 128 + wn * 64;
#pragma unroll
          for (int fn = 0; fn < 4; ++fn) part += acc[fm][fn][r] * w3r[fn * 16 + lr];
        }
      }
    }
#pragma unroll
    for (int off = 1; off < 64; off <<= 1) part += __shfl_xor(part, off);
    if (l == 0) red[w] = part;
    __syncthreads();
    if (t == 0) klp[tl * 512 + s] = red[0] + red[1] + red[2] + red[3];
  }
}

// y += sum_i db[i]*ky[i];  lp += sum_i db[i]*(klp[i][0][s] + klp[i][1][s])
__global__ __launch_bounds__(256) void step_update(float* __restrict__ y,
                                                   float* __restrict__ lp,
                                                   const float* __restrict__ ky,
                                                   const float* __restrict__ klp_part,
                                                   Coef6 db) {
  int i = blockIdx.x * 256 + threadIdx.x;
  if (i < 65536) {
    float a = y[i];
#pragma unroll
    for (int j = 0; j < 6; ++j) a += db.v[j] * ky[j * 65536 + i];
    y[i] = a;
  }
  if (i < 512) {
    float l = lp[i];
#pragma unroll
    for (int j = 0; j < 6; ++j) {
      const float* kp = klp_part + j * 1024;
      l += db.v[j] * (kp[i] + kp[512 + i]);
    }
    lp[i] = l;
  }
}

__global__ __launch_bounds__(64) void finalize(const float* __restrict__ y,
                                               const float* __restrict__ lp,
                                               float* __restrict__ out) {
  int s = blockIdx.x, l = threadIdx.x;
  float v0 = y[s * 128 + l], v1 = y[s * 128 + 64 + l];
  float sum = v0 * v0 + v1 * v1;
#pragma unroll
  for (int off = 32; off; off >>= 1) sum += __shfl_down(sum, off);
  if (l == 0) out[s] = lp[s] + (-0.5f) * (1.8378770664093453f + sum);
}

// ---------------------------------------------------------------------------
extern "C" void kernel_launch(void* const* d_in, const int* in_sizes, int n_in,
                              void* d_out, int out_size, void* d_ws, size_t ws_size,
                              hipStream_t stream) {
  const float* y_in = (const float*)d_in[0];
  const float* Ws0 = (const float*)d_in[1];
  const float* bs0 = (const float*)d_in[2];
  const float* Ws1 = (const float*)d_in[3];
  const float* bs1 = (const float*)d_in[4];
  const float* Ws2 = (const float*)d_in[5];
  const float* bs2 = (const float*)d_in[6];
  const float* Ws3 = (const float*)d_in[7];
  const float* bs3 = (const float*)d_in[8];
  float* out = (float*)d_out;

  char* ws = (char*)d_ws;
  size_t off = 0;
  auto alloc = [&](size_t bytes) {
    void* p = ws + off;
    off = (off + bytes + 255) & ~(size_t)255;
    return p;
  };
  float* y  = (float*)alloc(65536 * 4);
  float* lp = (float*)alloc(512 * 4);
  unsigned short* h0hi = (unsigned short*)alloc(262144 * 2);
  unsigned short* h0lo = (unsigned short*)alloc(262144 * 2);
  unsigned short* h1hi = (unsigned short*)alloc(262144 * 2);
  unsigned short* h1lo = (unsigned short*)alloc(262144 * 2);
  unsigned short* h2hi = (unsigned short*)alloc(262144 * 2);
  unsigned short* h2lo = (unsigned short*)alloc(262144 * 2);
  float* ky  = (float*)alloc(6 * 65536 * 4);
  float* klp = (float*)alloc(6 * 1024 * 4);
  unsigned short* w0y  = (unsigned short*)alloc(65536 * 2);
  unsigned short* w0tH = (unsigned short*)alloc(65536 * 2);
  unsigned short* w0tL = (unsigned short*)alloc(65536 * 2);
  unsigned short* w1tH = (unsigned short*)alloc(262144 * 2);
  unsigned short* w1tL = (unsigned short*)alloc(262144 * 2);
  unsigned short* w2tH = (unsigned short*)alloc(262144 * 2);
  unsigned short* w2tL = (unsigned short*)alloc(262144 * 2);
  unsigned short* w3tH = (unsigned short*)alloc(65536 * 2);
  unsigned short* w3tL = (unsigned short*)alloc(65536 * 2);
  unsigned short* J1T  = (unsigned short*)alloc((size_t)512 * 65536 * 2);  // 64 MiB
  (void)ws_size; (void)in_sizes; (void)n_in; (void)out_size;

  static const double DT = -0.1;
  static const double TC[6] = {0.0, 0.161, 0.327, 0.9, 0.9800255409045097, 1.0};
  static const double TA[6][5] = {
      {0, 0, 0, 0, 0},
      {0.161, 0, 0, 0, 0},
      {-0.008480655492356989, 0.335480655492357, 0, 0, 0},
      {2.8971530571054935, -6.359448489975075, 4.3622954328695815, 0, 0},
      {5.325864828439257, -11.748883564062828, 7.4955393428898365, -0.09249506636175525, 0},
      {5.86145544294642, -12.92096931784711, 8.159367898576159, -0.071584973281401,
       -0.028269050394068383}};
  static const double TB[6] = {0.09646076681806523, 0.01, 0.4798896504144996,
                               1.379008574103742, -3.290069515436081, 2.324710524099774};

  init_state<<<dim3(256), dim3(256), 0, stream>>>(y_in, y, lp);

  for (int blk = 0; blk < 2; ++blk) {
    const float* W0 = Ws0 + blk * 129 * 512;
    const float* b0 = bs0 + blk * 512;
    const float* W1 = Ws1 + blk * 262144;
    const float* b1 = bs1 + blk * 512;
    const float* W2 = Ws2 + blk * 262144;
    const float* b2 = bs2 + blk * 512;
    const float* W3 = Ws3 + blk * 65536;
    const float* b3 = bs3 + blk * 128;

    cast_weights<<<dim3(2816), dim3(256), 0, stream>>>(
        W0, W1, W2, W3, w0y, w0tH, w0tL, w1tH, w1tL, w2tH, w2tL, w3tH, w3tL);

    for (int n = 0; n < 10; ++n) {
      float t = 1.0f + (-0.1f) * (float)n;
      for (int i = 0; i < 6; ++i) {
        float ti = t + (float)(TC[i] * DT);
        Coef5 ca;
        for (int j = 0; j < 5; ++j) ca.v[j] = (j < i) ? (float)(DT * TA[i][j]) : 0.f;

        fwd_mfma<true, true><<<dim3(8, 8), 256, 0, stream>>>(
            y, ky, nullptr, nullptr, w0tH, w0tL, b0, W0, ti, ca, i,
            nullptr, h0hi, h0lo, 512, 128);
        fwd_mfma<true, false><<<dim3(8, 8), 256, 0, stream>>>(
            nullptr, nullptr, h0hi, h0lo, w1tH, w1tL, b1, nullptr, 0.f, ca, 0,
            nullptr, h1hi, h1lo, 512, 512);
        fwd_mfma<true, false><<<dim3(8, 8), 256, 0, stream>>>(
            nullptr, nullptr, h1hi, h1lo, w2tH, w2tL, b2, nullptr, 0.f, ca, 0,
            nullptr, h2hi, h2lo, 512, 512);
        fwd_mfma<false, false><<<dim3(2, 8), 256, 0, stream>>>(
            nullptr, nullptr, h2hi, h2lo, w3tH, w3tL, b3, nullptr, 0.f, ca, 0,
            ky + i * 65536, nullptr, nullptr, 128, 512);
        jac_k<0><<<dim3(2, 512), 256, 0, stream>>>(w1tH, w0y, h0hi, h1hi, nullptr,
                                                   J1T, nullptr);
        jac_k<1><<<dim3(2, 512), 256, 0, stream>>>(w2tH, J1T, nullptr, h2hi, W3,
                                                   nullptr, klp + i * 1024);
      }
      Coef6 db;
      for (int i2 = 0; i2 < 6; ++i2) db.v[i2] = (float)(DT * TB[i2]);
      step_update<<<dim3(256), dim3(256), 0, stream>>>(y, lp, ky, klp, db);
    }
  }
  finalize<<<dim3(512), dim3(64), 0, stream>>>(y, lp, out);
}

// Round 4
// 13073.550 us; speedup vs baseline: 2.1756x; 1.2467x over previous
//
#include <hip/hip_runtime.h>

// ---------------------------------------------------------------------------
// CNF forward: 2 blocks x Tsit5(10 steps x 6 stages).
// Round 4:
//  - jacA+jacB fused into one kernel via trace = <J1, G> with
//    G = W2 * diag(D2) * W3^T: dual MFMA accumulators, in-register dot,
//    J1T intermediate (64 MiB/stage write+read) eliminated.
//  - fwd BK 32->128: 4x fewer vmcnt-drain barriers; L0 via prep_split.
// ---------------------------------------------------------------------------

using short8 = __attribute__((ext_vector_type(8))) short;
using u16x8  = __attribute__((ext_vector_type(8))) unsigned short;
using f32x4v = __attribute__((ext_vector_type(4))) float;

__device__ __forceinline__ unsigned short f2bf(float f) {
  union { float f; unsigned u; } v; v.f = f;
  unsigned r = v.u + 0x7fffu + ((v.u >> 16) & 1u);
  return (unsigned short)(r >> 16);
}
__device__ __forceinline__ float bf2f(unsigned short h) {
  union { unsigned u; float f; } v; v.u = ((unsigned)h) << 16; return v.f;
}

typedef const __attribute__((address_space(1))) void gas_t;
typedef __attribute__((address_space(3))) void las_t;
__device__ __forceinline__ void gl_lds16(const void* g, void* l) {
  __builtin_amdgcn_global_load_lds((gas_t*)g, (las_t*)l, 16, 0, 0);
}

struct Coef5 { float v[5]; };
struct Coef6 { float v[6]; };

// ---------------------------------------------------------------------------
__global__ __launch_bounds__(256) void init_state(const float* __restrict__ y_in,
                                                  float* __restrict__ y,
                                                  float* __restrict__ lp) {
  int i = blockIdx.x * 256 + threadIdx.x;
  if (i < 512 * 128) y[i] = y_in[i];
  if (i < 512) lp[i] = 0.f;
}

// Weight prep (per ODE block):
//  w0y[j][a] = bf16(W0[1+j][a])   128x512   (jac GEMM1 B)
//  w0t[n][k] = split(W0[1+k][n])  512x128   (fwd L0 B)
//  w1t[b][a] = split(W1[a][b])    512x512   (fwd L1 B; hi = jac GEMM1 A)
//  w2t[c][b] = split(W2[b][c])    512x512   (fwd L2 B)
//  w3t[j][c] = split(W3[c][j])    128x512   (fwd L3 B; hi = jac GEMM2 B)
//  w2n[b][c] = bf16(W2[b][c])     512x512   (jac GEMM2 A, natural layout)
__global__ __launch_bounds__(256) void cast_weights(
    const float* __restrict__ W0, const float* __restrict__ W1,
    const float* __restrict__ W2, const float* __restrict__ W3,
    unsigned short* __restrict__ w0y,
    unsigned short* __restrict__ w0tH, unsigned short* __restrict__ w0tL,
    unsigned short* __restrict__ w1tH, unsigned short* __restrict__ w1tL,
    unsigned short* __restrict__ w2tH, unsigned short* __restrict__ w2tL,
    unsigned short* __restrict__ w3tH, unsigned short* __restrict__ w3tL,
    unsigned short* __restrict__ w2n) {
  int i = blockIdx.x * 256 + threadIdx.x;
  if (i < 65536) {
    int j = i >> 9, a = i & 511;
    w0y[i] = f2bf(W0[(1 + j) * 512 + a]);
    return;
  }
  i -= 65536;
  if (i >= 2 * 65536 + 2 * 262144) {
    int q = i - (2 * 65536 + 2 * 262144);
    if (q < 262144) w2n[q] = f2bf(W2[q]);
    return;
  }
  float v;
  unsigned short* dh;
  unsigned short* dl;
  int di;
  if (i < 65536) {
    int n = i >> 7, k = i & 127;
    v = W0[(1 + k) * 512 + n]; dh = w0tH; dl = w0tL; di = i;
  } else if (i < 65536 + 262144) {
    int q = i - 65536; int n = q >> 9, k = q & 511;
    v = W1[k * 512 + n]; dh = w1tH; dl = w1tL; di = q;
  } else if (i < 65536 + 2 * 262144) {
    int q = i - 65536 - 262144; int c = q >> 9, b = q & 511;
    v = W2[b * 512 + c]; dh = w2tH; dl = w2tL; di = q;
  } else {
    int q = i - 65536 - 2 * 262144; int j = q >> 9, c = q & 511;
    v = W3[c * 128 + j]; dh = w3tH; dl = w3tL; di = q;
  }
  unsigned short hi = f2bf(v);
  dh[di] = hi;
  dl[di] = f2bf(v - bf2f(hi));
}

// yi = y + sum_{j<nc} ca[j]*ky[j], split into bf16 hi/lo.
__global__ __launch_bounds__(256) void prep_split(
    const float* __restrict__ y, const float* __restrict__ ky, Coef5 ca, int nc,
    unsigned short* __restrict__ yihi, unsigned short* __restrict__ yilo) {
  int i = (blockIdx.x * 256 + threadIdx.x) * 4;
  if (i >= 65536) return;
  float4 v = *(const float4*)&y[i];
  for (int j = 0; j < nc; ++j) {
    float4 u = *(const float4*)&ky[j * 65536 + i];
    v.x = fmaf(ca.v[j], u.x, v.x); v.y = fmaf(ca.v[j], u.y, v.y);
    v.z = fmaf(ca.v[j], u.z, v.z); v.w = fmaf(ca.v[j], u.w, v.w);
  }
  float a[4] = {v.x, v.y, v.z, v.w};
  ushort4 h4, l4;
  unsigned short* hp = (unsigned short*)&h4;
  unsigned short* lp4 = (unsigned short*)&l4;
#pragma unroll
  for (int e = 0; e < 4; ++e) {
    unsigned short h = f2bf(a[e]);
    hp[e] = h;
    lp4[e] = f2bf(a[e] - bf2f(h));
  }
  *(ushort4*)&yihi[i] = h4;
  *(ushort4*)&yilo[i] = l4;
}

// ---------------------------------------------------------------------------
// fwd split-bf16 MFMA GEMM: C[M,N] = act(A @ W + bias (+ t*wrow0)).
// Tile 64x64, BK=128 (4 vmcnt-drains for K=512), 4 waves 2x2, wave 32x32.
// XOR-granule-swizzled global_load_lds staging (16 granules/row of 16B).
// ---------------------------------------------------------------------------
template <bool RELU>
__global__ __launch_bounds__(256) void fwd_mfma(
    const unsigned short* __restrict__ Ahi, const unsigned short* __restrict__ Alo,
    const unsigned short* __restrict__ WtH, const unsigned short* __restrict__ WtL,
    const float* __restrict__ bias, const float* __restrict__ wrow0, float tval,
    float* __restrict__ Cf, unsigned short* __restrict__ Hhi,
    unsigned short* __restrict__ Hlo, int N, int K) {
  __shared__ unsigned short AsH[8192], AsL[8192], BsH[8192], BsL[8192];
  const int t = threadIdx.x, l = t & 63, w = t >> 6;
  const int wm = w >> 1, wn = w & 1, lr = l & 15, lg = l >> 4;
  const int m0 = blockIdx.y * 64, n0 = blockIdx.x * 64;

  f32x4v acc[2][2];
#pragma unroll
  for (int a = 0; a < 2; ++a)
#pragma unroll
    for (int b = 0; b < 2; ++b) acc[a][b] = f32x4v{0.f, 0.f, 0.f, 0.f};

  for (int k0 = 0; k0 < K; k0 += 128) {
    __syncthreads();
#pragma unroll
    for (int i = 0; i < 4; ++i) {
      int g = i * 256 + t;
      int row = g >> 4;
      int gc = (g & 15) ^ (row & 7);
      size_t aoff = (size_t)(m0 + row) * K + k0 + gc * 8;
      size_t boff = (size_t)(n0 + row) * K + k0 + gc * 8;
      int db = (i * 256 + (t & 192)) * 16;
      gl_lds16(Ahi + aoff, (char*)AsH + db);
      gl_lds16(Alo + aoff, (char*)AsL + db);
      gl_lds16(WtH + boff, (char*)BsH + db);
      gl_lds16(WtL + boff, (char*)BsL + db);
    }
    __syncthreads();
#pragma unroll
    for (int ks = 0; ks < 4; ++ks) {
      short8 ah[2], alo[2], bh[2], blo[2];
#pragma unroll
      for (int fm = 0; fm < 2; ++fm) {
        int row = wm * 32 + fm * 16 + lr;
        int byo = row * 256 + (((ks * 4 + lg) ^ (lr & 7)) << 4);
        ah[fm] = *(const short8*)((const char*)AsH + byo);
        alo[fm] = *(const short8*)((const char*)AsL + byo);
      }
#pragma unroll
      for (int fn = 0; fn < 2; ++fn) {
        int row = wn * 32 + fn * 16 + lr;
        int byo = row * 256 + (((ks * 4 + lg) ^ (lr & 7)) << 4);
        bh[fn] = *(const short8*)((const char*)BsH + byo);
        blo[fn] = *(const short8*)((const char*)BsL + byo);
      }
#pragma unroll
      for (int fm = 0; fm < 2; ++fm)
#pragma unroll
        for (int fn = 0; fn < 2; ++fn) {
          acc[fm][fn] = __builtin_amdgcn_mfma_f32_16x16x32_bf16(ah[fm], bh[fn],
                                                                acc[fm][fn], 0, 0, 0);
          acc[fm][fn] = __builtin_amdgcn_mfma_f32_16x16x32_bf16(ah[fm], blo[fn],
                                                                acc[fm][fn], 0, 0, 0);
          acc[fm][fn] = __builtin_amdgcn_mfma_f32_16x16x32_bf16(alo[fm], bh[fn],
                                                                acc[fm][fn], 0, 0, 0);
        }
    }
  }

#pragma unroll
  for (int fm = 0; fm < 2; ++fm)
#pragma unroll
    for (int fn = 0; fn < 2; ++fn) {
      int n = n0 + wn * 32 + fn * 16 + lr;
      float be = bias[n];
      if (wrow0) be = fmaf(tval, wrow0[n], be);
#pragma unroll
      for (int r = 0; r < 4; ++r) {
        int m = m0 + wm * 32 + fm * 16 + lg * 4 + r;
        float v = acc[fm][fn][r] + be;
        if (RELU) {
          v = fmaxf(v, 0.f);
          unsigned short h = f2bf(v);
          Hhi[m * N + n] = h;
          Hlo[m * N + n] = f2bf(v - bf2f(h));
        } else {
          Cf[m * N + n] = v;
        }
      }
    }
}

// ---------------------------------------------------------------------------
// Fused Jacobian-trace kernel. Per (chunk cb, sample s): two 128x128 GEMMs
// (K=512) with identical fragment geometry:
//   J1[b][j] = sum_a w1t[b][a] * (D0[a]*w0y[j][a])      (D1 applied in dot)
//   G [b][j] = sum_c w2n[b][c] * (D2[c]*w3t[j][c])
//   klp[cb][s] = sum_{b in chunk, j} D1[b] * J1[b][j] * G[b][j]
// Masks = activation-hi bf16 words, converted in LDS to 0xFFFF/0 for AND.
// ---------------------------------------------------------------------------
__device__ __forceinline__ void gemm_chunk(
    f32x4v (&acc)[4][4], const unsigned short* __restrict__ Abase,
    const unsigned short* __restrict__ Bbase, const unsigned short* MsK,
    unsigned short* As, unsigned short* Bs, int t, int w, int wm, int wn,
    int lr, int lg) {
  for (int k0 = 0; k0 < 512; k0 += 64) {
    __syncthreads();
#pragma unroll
    for (int i = 0; i < 4; ++i) {
      int g = i * 256 + t;
      int row = g >> 3;
      int gc = (g & 7) ^ (row & 7);
      gl_lds16(Abase + (size_t)row * 512 + k0 + gc * 8,
               (char*)As + (i * 256 + (t & 192)) * 16);
    }
#pragma unroll
    for (int i = 0; i < 4; ++i) {
      int g = i * 256 + t;
      int row = g >> 3;
      int gc = (g & 7) ^ (row & 7);
      gl_lds16(Bbase + (size_t)row * 512 + k0 + gc * 8,
               (char*)Bs + (i * 256 + (t & 192)) * 16);
    }
    __syncthreads();
#pragma unroll
    for (int ks = 0; ks < 2; ++ks) {
      u16x8 mv = *(const u16x8*)&MsK[k0 + ks * 32 + lg * 8];
      short8 af[4];
      u16x8 bf4[4];
#pragma unroll
      for (int fm = 0; fm < 4; ++fm) {
        int row = wm * 64 + fm * 16 + lr;
        af[fm] = *(const short8*)((const char*)As + row * 128 +
                                  (((ks * 4 + lg) ^ (lr & 7)) << 4));
      }
#pragma unroll
      for (int fn = 0; fn < 4; ++fn) {
        int row = wn * 64 + fn * 16 + lr;
        u16x8 bv = *(const u16x8*)((const char*)Bs + row * 128 +
                                   (((ks * 4 + lg) ^ (lr & 7)) << 4));
        bf4[fn] = bv & mv;
      }
#pragma unroll
      for (int fm = 0; fm < 4; ++fm)
#pragma unroll
        for (int fn = 0; fn < 4; ++fn)
          acc[fm][fn] = __builtin_amdgcn_mfma_f32_16x16x32_bf16(
              af[fm], (short8)bf4[fn], acc[fm][fn], 0, 0, 0);
    }
  }
}

__global__ __launch_bounds__(256, 2) void jac_fused(
    const unsigned short* __restrict__ w1t, const unsigned short* __restrict__ w0y,
    const unsigned short* __restrict__ w2n, const unsigned short* __restrict__ w3t,
    const unsigned short* __restrict__ d0m, const unsigned short* __restrict__ d1m,
    const unsigned short* __restrict__ d2m, float* __restrict__ klp) {
  __shared__ unsigned short As[8192], Bs[8192];
  __shared__ unsigned short Ms0[512], Ms1[512], Ms2[512];
  __shared__ float red[4];
  const int cb = blockIdx.x, s = blockIdx.y;
  const int t = threadIdx.x, l = t & 63, w = t >> 6;
  const int wm = w >> 1, wn = w & 1, lr = l & 15, lg = l >> 4;

  if (w == 0) gl_lds16(d0m + s * 512 + l * 8, Ms0);
  else if (w == 1) gl_lds16(d1m + s * 512 + l * 8, Ms1);
  else if (w == 2) gl_lds16(d2m + s * 512 + l * 8, Ms2);
  __syncthreads();
  {
    unsigned* M0 = (unsigned*)Ms0;
    unsigned* M1 = (unsigned*)Ms1;
    unsigned* M2 = (unsigned*)Ms2;
    unsigned v0 = M0[t], v1 = M1[t], v2 = M2[t];
    M0[t] = ((v0 & 0xFFFFu) ? 0xFFFFu : 0u) | ((v0 >> 16) ? 0xFFFF0000u : 0u);
    M1[t] = ((v1 & 0xFFFFu) ? 0xFFFFu : 0u) | ((v1 >> 16) ? 0xFFFF0000u : 0u);
    M2[t] = ((v2 & 0xFFFFu) ? 0xFFFFu : 0u) | ((v2 >> 16) ? 0xFFFF0000u : 0u);
  }
  // gemm_chunk opens with __syncthreads(): conversion visible before reads.

  f32x4v accJ[4][4], accG[4][4];
#pragma unroll
  for (int a = 0; a < 4; ++a)
#pragma unroll
    for (int b = 0; b < 4; ++b) {
      accJ[a][b] = f32x4v{0.f, 0.f, 0.f, 0.f};
      accG[a][b] = f32x4v{0.f, 0.f, 0.f, 0.f};
    }

  gemm_chunk(accJ, w1t + (size_t)cb * 65536, w0y, Ms0, As, Bs, t, w, wm, wn, lr, lg);
  gemm_chunk(accG, w2n + (size_t)cb * 65536, w3t, Ms2, As, Bs, t, w, wm, wn, lr, lg);

  float part = 0.f;
#pragma unroll
  for (int fm = 0; fm < 4; ++fm) {
    int bb = cb * 128 + wm * 64 + fm * 16 + lg * 4;
    ushort4 m4 = *(const ushort4*)&Ms1[bb];
    unsigned short mm[4] = {m4.x, m4.y, m4.z, m4.w};
#pragma unroll
    for (int r = 0; r < 4; ++r) {
      if (mm[r]) {
#pragma unroll
        for (int fn = 0; fn < 4; ++fn)
          part += accJ[fm][fn][r] * accG[fm][fn][r];
      }
    }
  }
#pragma unroll
  for (int off = 1; off < 64; off <<= 1) part += __shfl_xor(part, off);
  if (l == 0) red[w] = part;
  __syncthreads();
  if (t == 0) klp[cb * 512 + s] = red[0] + red[1] + red[2] + red[3];
}

// y += sum_i db[i]*ky[i];  lp += sum_i db[i]*(sum_{4 chunks} klp[i][cb][s])
__global__ __launch_bounds__(256) void step_update(float* __restrict__ y,
                                                   float* __restrict__ lp,
                                                   const float* __restrict__ ky,
                                                   const float* __restrict__ klp_part,
                                                   Coef6 db) {
  int i = blockIdx.x * 256 + threadIdx.x;
  if (i < 65536) {
    float a = y[i];
#pragma unroll
    for (int j = 0; j < 6; ++j) a += db.v[j] * ky[j * 65536 + i];
    y[i] = a;
  }
  if (i < 512) {
    float l = lp[i];
#pragma unroll
    for (int j = 0; j < 6; ++j) {
      const float* kp = klp_part + j * 2048;
      float tr = kp[i] + kp[512 + i] + kp[1024 + i] + kp[1536 + i];
      l += db.v[j] * tr;
    }
    lp[i] = l;
  }
}

__global__ __launch_bounds__(64) void finalize(const float* __restrict__ y,
                                               const float* __restrict__ lp,
                                               float* __restrict__ out) {
  int s = blockIdx.x, l = threadIdx.x;
  float v0 = y[s * 128 + l], v1 = y[s * 128 + 64 + l];
  float sum = v0 * v0 + v1 * v1;
#pragma unroll
  for (int off = 32; off; off >>= 1) sum += __shfl_down(sum, off);
  if (l == 0) out[s] = lp[s] + (-0.5f) * (1.8378770664093453f + sum);
}

// ---------------------------------------------------------------------------
extern "C" void kernel_launch(void* const* d_in, const int* in_sizes, int n_in,
                              void* d_out, int out_size, void* d_ws, size_t ws_size,
                              hipStream_t stream) {
  const float* y_in = (const float*)d_in[0];
  const float* Ws0 = (const float*)d_in[1];
  const float* bs0 = (const float*)d_in[2];
  const float* Ws1 = (const float*)d_in[3];
  const float* bs1 = (const float*)d_in[4];
  const float* Ws2 = (const float*)d_in[5];
  const float* bs2 = (const float*)d_in[6];
  const float* Ws3 = (const float*)d_in[7];
  const float* bs3 = (const float*)d_in[8];
  float* out = (float*)d_out;

  char* ws = (char*)d_ws;
  size_t off = 0;
  auto alloc = [&](size_t bytes) {
    void* p = ws + off;
    off = (off + bytes + 255) & ~(size_t)255;
    return p;
  };
  float* y  = (float*)alloc(65536 * 4);
  float* lp = (float*)alloc(512 * 4);
  unsigned short* yihi = (unsigned short*)alloc(65536 * 2);
  unsigned short* yilo = (unsigned short*)alloc(65536 * 2);
  unsigned short* h0hi = (unsigned short*)alloc(262144 * 2);
  unsigned short* h0lo = (unsigned short*)alloc(262144 * 2);
  unsigned short* h1hi = (unsigned short*)alloc(262144 * 2);
  unsigned short* h1lo = (unsigned short*)alloc(262144 * 2);
  unsigned short* h2hi = (unsigned short*)alloc(262144 * 2);
  unsigned short* h2lo = (unsigned short*)alloc(262144 * 2);
  float* ky  = (float*)alloc(6 * 65536 * 4);
  float* klp = (float*)alloc(6 * 2048 * 4);
  unsigned short* w0y  = (unsigned short*)alloc(65536 * 2);
  unsigned short* w0tH = (unsigned short*)alloc(65536 * 2);
  unsigned short* w0tL = (unsigned short*)alloc(65536 * 2);
  unsigned short* w1tH = (unsigned short*)alloc(262144 * 2);
  unsigned short* w1tL = (unsigned short*)alloc(262144 * 2);
  unsigned short* w2tH = (unsigned short*)alloc(262144 * 2);
  unsigned short* w2tL = (unsigned short*)alloc(262144 * 2);
  unsigned short* w3tH = (unsigned short*)alloc(65536 * 2);
  unsigned short* w3tL = (unsigned short*)alloc(65536 * 2);
  unsigned short* w2n  = (unsigned short*)alloc(262144 * 2);
  (void)ws_size; (void)in_sizes; (void)n_in; (void)out_size;

  static const double DT = -0.1;
  static const double TC[6] = {0.0, 0.161, 0.327, 0.9, 0.9800255409045097, 1.0};
  static const double TA[6][5] = {
      {0, 0, 0, 0, 0},
      {0.161, 0, 0, 0, 0},
      {-0.008480655492356989, 0.335480655492357, 0, 0, 0},
      {2.8971530571054935, -6.359448489975075, 4.3622954328695815, 0, 0},
      {5.325864828439257, -11.748883564062828, 7.4955393428898365, -0.09249506636175525, 0},
      {5.86145544294642, -12.92096931784711, 8.159367898576159, -0.071584973281401,
       -0.028269050394068383}};
  static const double TB[6] = {0.09646076681806523, 0.01, 0.4798896504144996,
                               1.379008574103742, -3.290069515436081, 2.324710524099774};

  init_state<<<dim3(256), dim3(256), 0, stream>>>(y_in, y, lp);

  for (int blk = 0; blk < 2; ++blk) {
    const float* W0 = Ws0 + blk * 129 * 512;
    const float* b0 = bs0 + blk * 512;
    const float* W1 = Ws1 + blk * 262144;
    const float* b1 = bs1 + blk * 512;
    const float* W2 = Ws2 + blk * 262144;
    const float* b2 = bs2 + blk * 512;
    const float* W3 = Ws3 + blk * 65536;
    const float* b3 = bs3 + blk * 128;

    cast_weights<<<dim3(3840), dim3(256), 0, stream>>>(
        W0, W1, W2, W3, w0y, w0tH, w0tL, w1tH, w1tL, w2tH, w2tL, w3tH, w3tL, w2n);

    for (int n = 0; n < 10; ++n) {
      float t = 1.0f + (-0.1f) * (float)n;
      for (int i = 0; i < 6; ++i) {
        float ti = t + (float)(TC[i] * DT);
        Coef5 ca;
        for (int j = 0; j < 5; ++j) ca.v[j] = (j < i) ? (float)(DT * TA[i][j]) : 0.f;

        prep_split<<<dim3(64), dim3(256), 0, stream>>>(y, ky, ca, i, yihi, yilo);
        fwd_mfma<true><<<dim3(8, 8), 256, 0, stream>>>(
            yihi, yilo, w0tH, w0tL, b0, W0, ti, nullptr, h0hi, h0lo, 512, 128);
        fwd_mfma<true><<<dim3(8, 8), 256, 0, stream>>>(
            h0hi, h0lo, w1tH, w1tL, b1, nullptr, 0.f, nullptr, h1hi, h1lo, 512, 512);
        fwd_mfma<true><<<dim3(8, 8), 256, 0, stream>>>(
            h1hi, h1lo, w2tH, w2tL, b2, nullptr, 0.f, nullptr, h2hi, h2lo, 512, 512);
        fwd_mfma<false><<<dim3(2, 8), 256, 0, stream>>>(
            h2hi, h2lo, w3tH, w3tL, b3, nullptr, 0.f, ky + i * 65536, nullptr,
            nullptr, 128, 512);
        jac_fused<<<dim3(4, 512), 256, 0, stream>>>(
            w1tH, w0y, w2n, w3tH, h0hi, h1hi, h2hi, klp + i * 2048);
      }
      Coef6 db;
      for (int i2 = 0; i2 < 6; ++i2) db.v[i2] = (float)(DT * TB[i2]);
      step_update<<<dim3(256), dim3(256), 0, stream>>>(y, lp, ky, klp, db);
    }
  }
  finalize<<<dim3(512), dim3(64), 0, stream>>>(y, lp, out);
}